// Round 6
// baseline (365.910 us; speedup 1.0000x reference)
//
#include <hip/hip_runtime.h>

typedef unsigned short u16;
typedef __attribute__((ext_vector_type(4))) float floatx4;
typedef __attribute__((ext_vector_type(4))) unsigned short u16x4;
typedef __attribute__((ext_vector_type(8))) short short8;
typedef __attribute__((ext_vector_type(8))) __bf16 bf16x8;

#define B_SZ 8
#define C_LEN 2048
#define Q_LEN 512
#define D_DIM 1024
#define K4 (4 * D_DIM)

static __device__ __forceinline__ u16 f2bf(float f) {
    union { float f; unsigned int u; } v; v.f = f;
    unsigned int r = v.u + 0x7FFFu + ((v.u >> 16) & 1u);  // round-to-nearest-even
    return (u16)(r >> 16);
}
static __device__ __forceinline__ float bf2f(u16 h) {
    union { unsigned int u; float f; } v; v.u = ((unsigned int)h) << 16;
    return v.f;
}

// async global->LDS, 16B per lane; LDS dest = wave-uniform base + lane*16
static __device__ __forceinline__ void async16(const void* g, void* l) {
    __builtin_amdgcn_global_load_lds(
        (const __attribute__((address_space(1))) unsigned int*)g,
        (__attribute__((address_space(3))) unsigned int*)(unsigned int)(unsigned long long)l,
        16, 0, 0);
}

// ---------- fused prep: precast_c | precast_q | transpose_q | zero q2c ----------
__global__ __launch_bounds__(256) void prep_kernel(
    const float* __restrict__ c, const float* __restrict__ q,
    const float* __restrict__ w_cq, const float* __restrict__ w_c, const float* __restrict__ w_q,
    u16* __restrict__ cbf, u16* __restrict__ qwbf, u16* __restrict__ qT,
    float* __restrict__ rowterm, float* __restrict__ colterm, float* __restrict__ q2c) {
    int blk = blockIdx.x;
    int tid = threadIdx.x;
    if (blk < 4096) {
        // precast_c: cbf = bf16(c); rowterm = c . w_c
        int row = blk * 4 + (tid >> 6);
        int lane = tid & 63;
        const float* src = c + (size_t)row * D_DIM;
        u16* dst = cbf + (size_t)row * D_DIM;
        float s = 0.f;
        #pragma unroll
        for (int j = 0; j < 4; ++j) {
            int idx = j * 256 + lane * 4;
            floatx4 a = *(const floatx4*)(src + idx);
            floatx4 w = *(const floatx4*)(w_c + idx);
            s += a[0]*w[0] + a[1]*w[1] + a[2]*w[2] + a[3]*w[3];
            u16x4 o;
            #pragma unroll
            for (int e = 0; e < 4; ++e) o[e] = f2bf(a[e]);
            *(u16x4*)(dst + idx) = o;
        }
        for (int off = 32; off; off >>= 1) s += __shfl_down(s, off);
        if (lane == 0) rowterm[row] = s;
    } else if (blk < 5120) {
        // precast_q: qwbf = bf16(q .* w_cq); colterm = q . w_q
        int row = (blk - 4096) * 4 + (tid >> 6);
        int lane = tid & 63;
        const float* src = q + (size_t)row * D_DIM;
        u16* dst = qwbf + (size_t)row * D_DIM;
        float s = 0.f;
        #pragma unroll
        for (int j = 0; j < 4; ++j) {
            int idx = j * 256 + lane * 4;
            floatx4 a  = *(const floatx4*)(src + idx);
            floatx4 wc = *(const floatx4*)(w_cq + idx);
            floatx4 wq = *(const floatx4*)(w_q + idx);
            s += a[0]*wq[0] + a[1]*wq[1] + a[2]*wq[2] + a[3]*wq[3];
            u16x4 o;
            #pragma unroll
            for (int e = 0; e < 4; ++e) o[e] = f2bf(a[e] * wc[e]);
            *(u16x4*)(dst + idx) = o;
        }
        for (int off = 32; off; off >>= 1) s += __shfl_down(s, off);
        if (lane == 0) colterm[row] = s;
    } else if (blk < 9216) {
        // transpose_q: qT[b,d,q] = bf16(q[b,q,d])
        __shared__ float tile[32][33];
        int t = blk - 5120;
        int q0 = (t & 15) * 32;
        int d0 = ((t >> 4) & 31) * 32;
        int b = t >> 9;
        int tx = tid & 31, ty = tid >> 5;  // 32 x 8
        const float* qb = q + (size_t)b * Q_LEN * D_DIM;
        #pragma unroll
        for (int j = 0; j < 4; ++j) {
            int row = ty + j * 8;
            tile[row][tx] = qb[(size_t)(q0 + row) * D_DIM + d0 + tx];
        }
        __syncthreads();
        u16* qTb = qT + (size_t)b * D_DIM * Q_LEN;
        #pragma unroll
        for (int j = 0; j < 4; ++j) {
            int row = ty + j * 8;
            qTb[(size_t)(d0 + row) * Q_LEN + q0 + tx] = f2bf(tile[tx][row]);
        }
    } else {
        // zero q2c (8192 floats)
        int i = (blk - 9216) * 256 + tid;
        q2c[i] = 0.0f;
    }
}

// ---------- fused W prep: Wm[b,n,k] = bf16(W1 + W4*q2c); Wbf[n,kk] = bf16(W[n,1024+kk]) ----------
__global__ __launch_bounds__(256) void wmerge_all(const float* __restrict__ W, const float* __restrict__ q2c,
                                                  u16* __restrict__ Wm, u16* __restrict__ Wbf) {
    int n = blockIdx.x;             // 1024 rows
    int k = threadIdx.x * 4;        // 0..1023
    const float* wr = W + (size_t)n * K4;
    floatx4 w1 = *(const floatx4*)(wr + k);
    floatx4 w4 = *(const floatx4*)(wr + 3072 + k);
    #pragma unroll
    for (int p = 0; p < 2; ++p) {
        int kk = p * 1024 + k;
        floatx4 v = *(const floatx4*)(wr + 1024 + kk);
        u16x4 o;
        #pragma unroll
        for (int e = 0; e < 4; ++e) o[e] = f2bf(v[e]);
        *(u16x4*)(Wbf + (size_t)n * 2048 + kk) = o;
    }
    #pragma unroll
    for (int b = 0; b < 8; ++b) {
        floatx4 g = *(const floatx4*)(q2c + (size_t)b * D_DIM + k);
        u16x4 o;
        #pragma unroll
        for (int e = 0; e < 4; ++e) o[e] = f2bf(w1[e] + w4[e] * g[e]);
        *(u16x4*)(Wm + (size_t)b * 1048576 + (size_t)n * 1024 + k) = o;
    }
}

// ---------- unified async bf16 GEMM, C = A @ B^T, 128x128 tile, BK=64, swizzled LDS ----------
// 1-D grid, XCD-pinned: b = lin & 7.
// LDS: tile [128 rows][8 chunks of 16B]; logical chunk cb stored at phys cb^(row&7).
// MODE 0: S    = cbf @ qwbf^T                     out fp32 [2048,512]
// MODE 1: cc2q = bf16(cbf * (P @ qT^T))           out bf16 [2048,1024]
// MODE 2: z    = cbf@Wm^T + P@W2q^T + cc2q@W3^T + b_l   (K = 1024+512+1024)
// MODE 3: W2q  = Wbf(W2 cols) @ q^T (fp32 B, manual staging)  out bf16 [1024,512]
template<int MODE>
__global__ __launch_bounds__(256) void gemm_async(
    const u16* __restrict__ A0, const u16* __restrict__ A1, const u16* __restrict__ A2,
    const u16* __restrict__ B0, const u16* __restrict__ B1, const u16* __restrict__ B2,
    const float* __restrict__ fB,
    float* __restrict__ of, u16* __restrict__ ob, const float* __restrict__ bias) {
    constexpr int NSEC = (MODE == 2) ? 3 : 1;
    constexpr int LDO  = (MODE == 0 || MODE == 3) ? 512 : 1024;
    constexpr int NTILES = (MODE == 0 || MODE == 3) ? 4 : 8;
    __shared__ u16 As[128 * 64];
    __shared__ u16 Bs[128 * 64];
    const int tid  = threadIdx.x;
    const int lane = tid & 63;
    const int wave = tid >> 6;
    const int lin  = blockIdx.x;
    const int b    = lin & 7;            // XCD pin
    const int rem  = lin >> 3;
    const int n0   = (rem % NTILES) * 128;
    const int m0   = (rem / NTILES) * 128;

    const u16* Aarr[NSEC];
    const u16* Barr[NSEC];
    const float* Bf = nullptr;
    int lda_[NSEC], ldb_[NSEC], ks_[NSEC];
    if constexpr (MODE == 0) {
        Aarr[0] = A0 + (size_t)b * C_LEN * D_DIM; lda_[0] = 1024;
        Barr[0] = B0 + (size_t)b * Q_LEN * D_DIM; ldb_[0] = 1024; ks_[0] = 1024;
    } else if constexpr (MODE == 1) {
        Aarr[0] = A0 + (size_t)b * C_LEN * Q_LEN; lda_[0] = 512;
        Barr[0] = B0 + (size_t)b * D_DIM * Q_LEN; ldb_[0] = 512;  ks_[0] = 512;
    } else if constexpr (MODE == 3) {
        Aarr[0] = A0;                             lda_[0] = 2048;  // Wbf (W2 cols), shared
        Barr[0] = nullptr;                        ldb_[0] = 1024;  ks_[0] = 1024;
        Bf = fB + (size_t)b * Q_LEN * D_DIM;                       // q fp32
    } else {
        Aarr[0] = A0 + (size_t)b * C_LEN * D_DIM; lda_[0] = 1024;  // cbf
        Barr[0] = B0 + (size_t)b * D_DIM * D_DIM; ldb_[0] = 1024;  ks_[0] = 1024;  // Wm
        Aarr[1] = A1 + (size_t)b * C_LEN * Q_LEN; lda_[1] = 512;   // P
        Barr[1] = B1 + (size_t)b * D_DIM * Q_LEN; ldb_[1] = 512;   ks_[1] = 512;   // W2q
        Aarr[2] = A2 + (size_t)b * C_LEN * D_DIM; lda_[2] = 1024;  // cc2q
        Barr[2] = B2 + 1024;                      ldb_[2] = 2048;  ks_[2] = 1024;  // W3 (shared)
    }

    // staging geometry: 16 chunks of 8 rows; wave w stages chunks 4w..4w+3
    const int srow = lane >> 3;                    // 0..7 row-within-chunk
    const int ssc  = ((lane & 7) ^ srow) * 8;      // swizzled source column (u16/f32 units)

    floatx4 acc[4][4];
    #pragma unroll
    for (int i = 0; i < 4; ++i)
        #pragma unroll
        for (int j = 0; j < 4; ++j)
            acc[i][j] = (floatx4)(0.0f);

    const int wrow = (wave >> 1) * 64;
    const int wcol = (wave & 1) * 64;
    const int quad = lane >> 4;
    const int lrow = lane & 15;
    const int sw7  = lane & 7;

    #pragma unroll
    for (int sec = 0; sec < NSEC; ++sec) {
        const u16* __restrict__ Ab = Aarr[sec];
        const u16* __restrict__ Bb = Barr[sec];
        const int LA = lda_[sec];
        const int LB = ldb_[sec];
        const int KS = ks_[sec];
        for (int k0 = 0; k0 < KS; k0 += 64) {
            #pragma unroll
            for (int cc = 0; cc < 4; ++cc) {
                int ch = wave * 4 + cc;
                int rr = ch * 8 + srow;
                async16(Ab + (size_t)(m0 + rr) * LA + k0 + ssc, &As[ch * 512]);
            }
            if constexpr (MODE == 3) {
                #pragma unroll
                for (int cc = 0; cc < 4; ++cc) {
                    int ch = wave * 4 + cc;
                    int rr = ch * 8 + srow;
                    const float* src = Bf + (size_t)(n0 + rr) * 1024 + k0 + ssc;
                    floatx4 v0 = *(const floatx4*)src;
                    floatx4 v1 = *(const floatx4*)(src + 4);
                    u16x4 o0, o1;
                    #pragma unroll
                    for (int e = 0; e < 4; ++e) { o0[e] = f2bf(v0[e]); o1[e] = f2bf(v1[e]); }
                    *(u16x4*)&Bs[ch * 512 + lane * 8]     = o0;
                    *(u16x4*)&Bs[ch * 512 + lane * 8 + 4] = o1;
                }
            } else {
                #pragma unroll
                for (int cc = 0; cc < 4; ++cc) {
                    int ch = wave * 4 + cc;
                    int rr = ch * 8 + srow;
                    async16(Bb + (size_t)(n0 + rr) * LB + k0 + ssc, &Bs[ch * 512]);
                }
            }
            __syncthreads();
            #pragma unroll
            for (int h = 0; h < 2; ++h) {
                const int pc = ((h * 4 + quad) ^ sw7) * 8;   // physical column (u16)
                bf16x8 af[4], bfr[4];
                #pragma unroll
                for (int i = 0; i < 4; ++i)
                    af[i] = __builtin_bit_cast(bf16x8, *(const short8*)&As[(wrow + i*16 + lrow) * 64 + pc]);
                #pragma unroll
                for (int j = 0; j < 4; ++j)
                    bfr[j] = __builtin_bit_cast(bf16x8, *(const short8*)&Bs[(wcol + j*16 + lrow) * 64 + pc]);
                #pragma unroll
                for (int i = 0; i < 4; ++i)
                    #pragma unroll
                    for (int j = 0; j < 4; ++j)
                        acc[i][j] = __builtin_amdgcn_mfma_f32_16x16x32_bf16(af[i], bfr[j], acc[i][j], 0, 0, 0);
            }
            __syncthreads();
        }
    }

    // ---- epilogue; C/D layout: col = lane&15, row = quad*4 + reg ----
    float* ofb = nullptr; u16* obb = nullptr; const u16* cbr = nullptr;
    if (MODE == 0)      ofb = of + (size_t)b * C_LEN * Q_LEN;
    else if (MODE == 1) { obb = ob + (size_t)b * C_LEN * D_DIM; cbr = A1 + (size_t)b * C_LEN * D_DIM; }
    else if (MODE == 2) ofb = of + (size_t)b * C_LEN * D_DIM;
    else                obb = ob + (size_t)b * D_DIM * Q_LEN;
    #pragma unroll
    for (int i = 0; i < 4; ++i) {
        #pragma unroll
        for (int j = 0; j < 4; ++j) {
            #pragma unroll
            for (int e = 0; e < 4; ++e) {
                int gm = m0 + wrow + i * 16 + quad * 4 + e;
                int gn = n0 + wcol + j * 16 + lrow;
                float v = acc[i][j][e];
                if (MODE == 0)      ofb[(size_t)gm * LDO + gn] = v;
                else if (MODE == 1) {
                    float cv = bf2f(cbr[(size_t)gm * 1024 + gn]);
                    obb[(size_t)gm * LDO + gn] = f2bf(cv * v);
                }
                else if (MODE == 2) ofb[(size_t)gm * LDO + gn] = v + bias[gn];
                else                obb[(size_t)gm * LDO + gn] = f2bf(v);
            }
        }
    }
}

// ---------- softmax over Q per (b,c) row; also record rowmax ----------
__global__ void softmax_kernel(const float* __restrict__ S, const float* __restrict__ colterm,
                               u16* __restrict__ P, float* __restrict__ mbuf) {
    int row = blockIdx.x * 4 + (threadIdx.x >> 6);
    int lane = threadIdx.x & 63;
    int b = row >> 11;  // C_LEN = 2048
    const float* sp = S + (size_t)row * Q_LEN;
    const float* cp = colterm + (size_t)b * Q_LEN;
    float v[8];
    float m = -1e30f;
    #pragma unroll
    for (int j = 0; j < 8; ++j) {
        int idx = j * 64 + lane;
        v[j] = sp[idx] + cp[idx];
        m = fmaxf(m, v[j]);
    }
    for (int off = 32; off; off >>= 1) m = fmaxf(m, __shfl_xor(m, off));
    float s = 0.f;
    #pragma unroll
    for (int j = 0; j < 8; ++j) { v[j] = __expf(v[j] - m); s += v[j]; }
    for (int off = 32; off; off >>= 1) s += __shfl_xor(s, off);
    float inv = 1.0f / s;
    u16* pp = P + (size_t)row * Q_LEN;
    #pragma unroll
    for (int j = 0; j < 8; ++j) pp[j * 64 + lane] = f2bf(v[j] * inv);
    if (lane == 0) mbuf[row] = m;
}

// ---------- b_att[b,c] = softmax_c(rowmax + rowterm) ----------
__global__ __launch_bounds__(256) void batt_kernel(const float* __restrict__ mbuf,
                                                   const float* __restrict__ rowterm,
                                                   float* __restrict__ batt) {
    __shared__ float red[8];
    int b = blockIdx.x;
    int tid = threadIdx.x;
    const float* mb = mbuf + (size_t)b * C_LEN;
    const float* rt = rowterm + (size_t)b * C_LEN;
    float v[8];
    float m = -1e30f;
    #pragma unroll
    for (int j = 0; j < 8; ++j) { int idx = j * 256 + tid; v[j] = mb[idx] + rt[idx]; m = fmaxf(m, v[j]); }
    for (int off = 32; off; off >>= 1) m = fmaxf(m, __shfl_xor(m, off));
    int wave = tid >> 6, lane = tid & 63;
    if (lane == 0) red[wave] = m;
    __syncthreads();
    m = fmaxf(fmaxf(red[0], red[1]), fmaxf(red[2], red[3]));
    float s = 0.f;
    #pragma unroll
    for (int j = 0; j < 8; ++j) { v[j] = __expf(v[j] - m); s += v[j]; }
    for (int off = 32; off; off >>= 1) s += __shfl_xor(s, off);
    if (lane == 0) red[4 + wave] = s;
    __syncthreads();
    s = red[4] + red[5] + red[6] + red[7];
    float inv = 1.0f / s;
    float* bb = batt + (size_t)b * C_LEN;
    #pragma unroll
    for (int j = 0; j < 8; ++j) bb[j * 256 + tid] = v[j] * inv;
}

// ---------- q2c[b,d] = sum_c b_att[b,c] * cbf[b,c,d] (chunked + atomic) ----------
__global__ __launch_bounds__(256) void q2c_kernel(const float* __restrict__ batt,
                                                  const u16* __restrict__ cbf,
                                                  float* __restrict__ q2c) {
    int d  = blockIdx.x * 256 + threadIdx.x;
    int b  = blockIdx.y;
    int c0 = blockIdx.z * 256;
    const u16* cb = cbf + ((size_t)b * C_LEN + c0) * D_DIM + d;
    const float* bb = batt + (size_t)b * C_LEN + c0;
    float s = 0.f;
    #pragma unroll 4
    for (int i = 0; i < 256; ++i) s += bb[i] * bf2f(cb[(size_t)i * D_DIM]);
    atomicAdd(&q2c[(size_t)b * D_DIM + d], s);
}

extern "C" void kernel_launch(void* const* d_in, const int* in_sizes, int n_in,
                              void* d_out, int out_size, void* d_ws, size_t ws_size,
                              hipStream_t stream) {
    const float* c   = (const float*)d_in[0];
    const float* q   = (const float*)d_in[1];
    const float* wcq = (const float*)d_in[2];
    // b_cq (d_in[3]), b_c (d_in[5]), b_q (d_in[7]) cancel in both softmaxes — unused.
    const float* w_c = (const float*)d_in[4];
    const float* w_q = (const float*)d_in[6];
    const float* W_l = (const float*)d_in[8];
    const float* b_l = (const float*)d_in[9];
    float* out = (float*)d_out;

    char* ws = (char*)d_ws;
    // Region plan (lifetime-safe):
    //   [0,32M)     cbf        (prep .. gemm<2>)
    //   [32M,64M)   S fp32     (gemm<0> .. softmax); then cc2q bf16 (gemm<1> .. gemm<2>)
    //   [64M,72M)   qwbf       (prep .. gemm<0>);    then W2q bf16  (gemm<3> .. gemm<2>)
    //   [72M,88M)   P          (softmax .. gemm<2>)
    //   [88M,96M)   qT         (prep .. gemm<1>)
    //   [96M,112M)  Wm         (wmerge .. gemm<2>)
    //   [112M,116M) Wbf        (wmerge .. gemm<2>)
    //   [116M,..)   smalls     (total ~116.2 MiB)
    u16*   cbf     = (u16*)ws;
    float* S       = (float*)(ws + 33554432);
    u16*   cc2q    = (u16*)(ws + 33554432);
    u16*   qwbf    = (u16*)(ws + 67108864);
    u16*   W2q     = (u16*)(ws + 67108864);
    u16*   P       = (u16*)(ws + 75497472);
    u16*   qT      = (u16*)(ws + 92274688);
    u16*   Wm      = (u16*)(ws + 100663296);
    u16*   Wbf     = (u16*)(ws + 117440512);
    float* rowterm = (float*)(ws + 121634816);
    float* colterm = (float*)(ws + 121700352);
    float* mbuf    = (float*)(ws + 121716736);
    float* batt    = (float*)(ws + 121782272);
    float* q2c     = (float*)(ws + 121847808);

    prep_kernel<<<dim3(9248), dim3(256), 0, stream>>>(c, q, wcq, w_c, w_q,
                                                      cbf, qwbf, qT, rowterm, colterm, q2c);
    gemm_async<0><<<dim3(512), dim3(256), 0, stream>>>(cbf, nullptr, nullptr, qwbf, nullptr, nullptr,
                                                       nullptr, S, nullptr, nullptr);
    softmax_kernel<<<dim3(4096), dim3(256), 0, stream>>>(S, colterm, P, mbuf);
    batt_kernel<<<dim3(8), dim3(256), 0, stream>>>(mbuf, rowterm, batt);
    q2c_kernel<<<dim3(4, 8, 8), dim3(256), 0, stream>>>(batt, cbf, q2c);
    wmerge_all<<<dim3(1024), dim3(256), 0, stream>>>(W_l, q2c, Wm, Wbf);
    gemm_async<3><<<dim3(256), dim3(256), 0, stream>>>(Wbf, nullptr, nullptr, nullptr, nullptr, nullptr,
                                                       q, nullptr, W2q, nullptr);
    gemm_async<1><<<dim3(1024), dim3(256), 0, stream>>>(P, cbf, nullptr, qT, nullptr, nullptr,
                                                        nullptr, nullptr, cc2q, nullptr);
    gemm_async<2><<<dim3(1024), dim3(256), 0, stream>>>(cbf, P, cc2q, Wm, W2q, Wbf,
                                                        nullptr, out, nullptr, b_l);
}